// Round 7
// baseline (171.860 us; speedup 1.0000x reference)
//
#include <hip/hip_runtime.h>
#include <hip/hip_bf16.h>
#include <math.h>

#define NN 8192
#define DD 64
// 64x32 wave tiles: 4 row-frags x 2 col-frags of 16x16
#define BI_MAX 128
#define BJ_MAX 256
#define TRI2 16512                  // sum_{bi} (256 - 2*bi)
#define T1B TRI2                    // end of XX
#define T2B (2*TRI2)                // end of ZZ
#define TOTAL (T2B + BI_MAX*BJ_MAX) // 65792
#define NBLOCKS 768                 // 3 blocks/CU co-resident at 3 waves/SIMD
#define NWAVES (NBLOCKS*4)          // 3072
#define CHUNK ((TOTAL + NWAVES - 1)/NWAVES)  // 22 contiguous tiles per wave
#define NSLOT 32
#define SLOT_STRIDE 16              // floats -> 64B per slot

typedef __bf16 bf16x8 __attribute__((ext_vector_type(8)));
typedef float f32x4 __attribute__((ext_vector_type(4)));

#if defined(__has_builtin)
#if __has_builtin(__builtin_amdgcn_exp2f)
#define EXP2F __builtin_amdgcn_exp2f
#endif
#endif
#ifndef EXP2F
#define EXP2F exp2f
#endif

// ws layout:
//   [0,        1048576)  Xb  bf16 [8192][64]
//   [1048576,  2097152)  Zb  bf16 [8192][64]
//   [2097152, +32768)    na  f32  [8192]   ( = -log2(e) * ||x_i||^2 )
//   [+32768,  +65536)    nb  f32  [8192]
//   [+65536,  +71680)    partial f32 [3*NSLOT*SLOT_STRIDE]

__global__ __launch_bounds__(256) void prep_kernel(
        const float* __restrict__ X, const float* __restrict__ Z,
        __hip_bfloat16* __restrict__ Xb, __hip_bfloat16* __restrict__ Zb,
        float* __restrict__ na, float* __restrict__ nb,
        float* __restrict__ partial) {
    int tid = threadIdx.x;
    int gw = blockIdx.x * 4 + (tid >> 6);
    int lane = tid & 63;
    int r8 = lane >> 3, sub = lane & 7;
    int row = gw * 8 + r8;          // [0, 16384)
    const float* src = (row < NN) ? (X + (size_t)row * DD) : (Z + (size_t)(row - NN) * DD);
    __hip_bfloat16* dst = (row < NN) ? (Xb + (size_t)row * DD) : (Zb + (size_t)(row - NN) * DD);
    const float4* p = (const float4*)(src + sub * 8);
    float4 u = p[0], v = p[1];
    float w[8] = {u.x, u.y, u.z, u.w, v.x, v.y, v.z, v.w};
    unsigned int h[8];
    float s = 0.f;
    #pragma unroll
    for (int r = 0; r < 8; ++r) {
        __hip_bfloat16 b = __float2bfloat16(w[r]);
        h[r] = *(unsigned short*)&b;
        float xr = __bfloat162float(b);
        s = fmaf(xr, xr, s);
    }
    uint4 pk;
    pk.x = h[0] | (h[1] << 16); pk.y = h[2] | (h[3] << 16);
    pk.z = h[4] | (h[5] << 16); pk.w = h[6] | (h[7] << 16);
    *(uint4*)(dst + sub * 8) = pk;
    s += __shfl_xor(s, 1, 64);
    s += __shfl_xor(s, 2, 64);
    s += __shfl_xor(s, 4, 64);
    if (sub == 0) {
        float nv = -1.4426950408889634f * s;
        if (row < NN) na[row] = nv; else nb[row - NN] = nv;
    }
    if (blockIdx.x == 0) {
        for (int i = tid; i < 3 * NSLOT * SLOT_STRIDE; i += 256) partial[i] = 0.f;
    }
}

// Persistent independent waves, 64x32 tiles, contiguous runs along bj.
// Flat enumeration: [0,16512) XX upper (bj>=2bi), [16512,33024) ZZ upper,
// [33024,65792) XZ full. Map computed once per wave; then SALU increments.
// B-frags+col-norms double-buffered in registers: next tile's loads issue
// BEFORE current tile's MFMA -> L2 latency hides under compute (R3 lesson).
// 16-aligned frags vs the diagonal are purely above/diag/below -> frag-level
// triangle weights, per-element only on the (rare) rel==0 diagonal frags.
__global__ __launch_bounds__(256, 3) void mmd_kernel(
        const __hip_bfloat16* __restrict__ Xbh, const __hip_bfloat16* __restrict__ Zbh,
        const float* __restrict__ na, const float* __restrict__ nb,
        float* __restrict__ partial) {
    int tid = threadIdx.x;
    int wave = tid >> 6, lane = tid & 63;
    int lm = lane & 15, lk = lane >> 4;
    int gw = blockIdx.x * 4 + wave;
    const float C2 = 2.8853900817779268f;   // 2*log2(e)
    const __bf16* Xb = (const __bf16*)Xbh;
    const __bf16* Zb = (const __bf16*)Zbh;
    float s0 = 0.f, s1 = 0.f, s2 = 0.f;

    int t0 = gw * CHUNK;
    int nwork = TOTAL - t0;
    if (nwork > CHUNK) nwork = CHUNK;

    if (nwork > 0) {
        // ---- map t0 (once per wave) ----
        int combo, bi, bj;
        if (t0 < T2B) {
            combo = (t0 < T1B) ? 0 : 1;
            int tt = t0 - (combo ? T1B : 0);
            int rr = (int)((257.0f - sqrtf(66049.0f - 4.0f * (float)tt)) * 0.5f);
            rr = rr < 0 ? 0 : (rr > 127 ? 127 : rr);
            while (rr > 0 && rr * (257 - rr) > tt) --rr;
            while ((rr + 1) * (256 - rr) <= tt) ++rr;
            bi = rr; bj = 2 * rr + (tt - rr * (257 - rr));
        } else {
            combo = 2; int rem = t0 - T2B; bi = rem >> 8; bj = rem & 255;
        }

        bf16x8 af[2][4];
        f32x4 navv[4];
        float navmx[4];
        {
            const __bf16* A = (combo == 1) ? Zb : Xb;
            const float* sa = (combo == 1) ? nb : na;
            #pragma unroll
            for (int ks = 0; ks < 2; ++ks)
                #pragma unroll
                for (int rt = 0; rt < 4; ++rt)
                    af[ks][rt] = *(const bf16x8*)(A + (size_t)(bi * 64 + rt * 16 + lm) * DD + ks * 32 + lk * 8);
            #pragma unroll
            for (int rt = 0; rt < 4; ++rt) {
                navv[rt] = *(const f32x4*)(sa + bi * 64 + rt * 16 + lk * 4);
                navmx[rt] = fmaxf(fmaxf(navv[rt][0], navv[rt][1]), fmaxf(navv[rt][2], navv[rt][3]));
            }
        }

        bf16x8 b0[2][2], b1[2][2];
        float n0[2], n1[2];
        {
            const __bf16* Bp = (combo == 0) ? Xb : Zb;
            const float* sb = (combo == 0) ? na : nb;
            #pragma unroll
            for (int ks = 0; ks < 2; ++ks)
                #pragma unroll
                for (int ct = 0; ct < 2; ++ct)
                    b0[ks][ct] = *(const bf16x8*)(Bp + (size_t)(bj * 32 + ct * 16 + lm) * DD + ks * 32 + lk * 8);
            #pragma unroll
            for (int ct = 0; ct < 2; ++ct) n0[ct] = sb[bj * 32 + ct * 16 + lm];
        }

        int t = t0;
        int i = 0;

        auto step = [&](bf16x8 (&CURB)[2][2], float (&CURN)[2],
                        bf16x8 (&NXTB)[2][2], float (&NXTN)[2]) {
            // ---- next coords (SALU) ----
            int nt = t + 1;
            int ncombo = combo, nbi = bi, nbj = bj;
            bool rowch = false;
            if (nt == T1B || nt == T2B) { ncombo = combo + 1; nbi = 0; nbj = 0; rowch = true; }
            else {
                nbj = bj + 1;
                if (nbj == BJ_MAX) { nbi = bi + 1; nbj = (ncombo == 2) ? 0 : 2 * nbi; rowch = true; }
            }
            bool havenext = (i + 1 < nwork);

            // ---- prefetch next B + col-norms (before MFMA consumes CURB) ----
            if (havenext) {
                const __bf16* nBp = (ncombo == 0) ? Xb : Zb;
                const float* nsb = (ncombo == 0) ? na : nb;
                #pragma unroll
                for (int ks = 0; ks < 2; ++ks)
                    #pragma unroll
                    for (int ct = 0; ct < 2; ++ct)
                        NXTB[ks][ct] = *(const bf16x8*)(nBp + (size_t)(nbj * 32 + ct * 16 + lm) * DD + ks * 32 + lk * 8);
                #pragma unroll
                for (int ct = 0; ct < 2; ++ct) NXTN[ct] = nsb[nbj * 32 + ct * 16 + lm];
            }

            // ---- MFMA ----
            f32x4 acc[4][2] = {};
            #pragma unroll
            for (int ks = 0; ks < 2; ++ks)
                #pragma unroll
                for (int rt = 0; rt < 4; ++rt)
                    #pragma unroll
                    for (int ct = 0; ct < 2; ++ct)
                        acc[rt][ct] = __builtin_amdgcn_mfma_f32_16x16x32_bf16(
                            af[ks][rt], CURB[ks][ct], acc[rt][ct], 0, 0, 0);

            // ---- gated epilogue ----
            bool sym = (combo != 2);
            int dbase = sym ? (4 * bi - 2 * bj) : -1000000;
            float wAbove = sym ? 2.f : 1.f;
            float lsum = 0.f;
            #pragma unroll
            for (int rt = 0; rt < 4; ++rt) {
                #pragma unroll
                for (int ct = 0; ct < 2; ++ct) {
                    int rel = dbase + rt - ct;    // >0: below diag, ==0: diag frag, <0: above
                    if (rel > 0) continue;
                    float fm = fmaxf(fmaxf(acc[rt][ct][0], acc[rt][ct][1]),
                                     fmaxf(acc[rt][ct][2], acc[rt][ct][3]));
                    float fb = fmaf(fm, C2, navmx[rt] + CURN[ct]);
                    if (__any(fb > -30.f)) {
                        float base = CURN[ct];
                        float a0 = fmaf(acc[rt][ct][0], C2, navv[rt][0] + base);
                        float a1 = fmaf(acc[rt][ct][1], C2, navv[rt][1] + base);
                        float a2 = fmaf(acc[rt][ct][2], C2, navv[rt][2] + base);
                        float a3 = fmaf(acc[rt][ct][3], C2, navv[rt][3] + base);
                        float e0 = EXP2F(fminf(a0, 0.f));
                        float e1 = EXP2F(fminf(a1, 0.f));
                        float e2 = EXP2F(fminf(a2, 0.f));
                        float e3 = EXP2F(fminf(a3, 0.f));
                        if (rel == 0) {
                            int g0 = lk * 4;   // frag-local row; frag-local col = lm
                            e0 *= (g0 + 0 < lm) ? 2.f : ((g0 + 0 == lm) ? 1.f : 0.f);
                            e1 *= (g0 + 1 < lm) ? 2.f : ((g0 + 1 == lm) ? 1.f : 0.f);
                            e2 *= (g0 + 2 < lm) ? 2.f : ((g0 + 2 == lm) ? 1.f : 0.f);
                            e3 *= (g0 + 3 < lm) ? 2.f : ((g0 + 3 == lm) ? 1.f : 0.f);
                            lsum += (e0 + e1) + (e2 + e3);
                        } else {
                            lsum += wAbove * ((e0 + e1) + (e2 + e3));
                        }
                    }
                }
            }
            if (combo == 0) s0 += lsum; else if (combo == 1) s1 += lsum; else s2 += lsum;

            // ---- row/combo change: reload A panel + row norms ----
            if (rowch && havenext) {
                const __bf16* nA = (ncombo == 1) ? Zb : Xb;
                const float* nsa = (ncombo == 1) ? nb : na;
                #pragma unroll
                for (int ks = 0; ks < 2; ++ks)
                    #pragma unroll
                    for (int rt = 0; rt < 4; ++rt)
                        af[ks][rt] = *(const bf16x8*)(nA + (size_t)(nbi * 64 + rt * 16 + lm) * DD + ks * 32 + lk * 8);
                #pragma unroll
                for (int rt = 0; rt < 4; ++rt) {
                    navv[rt] = *(const f32x4*)(nsa + nbi * 64 + rt * 16 + lk * 4);
                    navmx[rt] = fmaxf(fmaxf(navv[rt][0], navv[rt][1]), fmaxf(navv[rt][2], navv[rt][3]));
                }
            }
            combo = ncombo; bi = nbi; bj = nbj; t = nt;
        };

        while (i < nwork) {
            step(b0, n0, b1, n1);
            ++i; if (i >= nwork) break;
            step(b1, n1, b0, n0);
            ++i;
        }
    }

    // ---- flush: wave reduce -> LDS -> 3 spread global atomics per block ----
    #pragma unroll
    for (int off = 32; off; off >>= 1) {
        s0 += __shfl_xor(s0, off, 64);
        s1 += __shfl_xor(s1, off, 64);
        s2 += __shfl_xor(s2, off, 64);
    }
    __shared__ float bsum[3];
    if (tid < 3) bsum[tid] = 0.f;
    __syncthreads();
    if (lane == 0) {
        atomicAdd(&bsum[0], s0);
        atomicAdd(&bsum[1], s1);
        atomicAdd(&bsum[2], s2);
    }
    __syncthreads();
    if (tid < 3)
        atomicAdd(&partial[(tid * NSLOT + (blockIdx.x & (NSLOT - 1))) * SLOT_STRIDE], bsum[tid]);
}

__global__ void final_kernel(const float* __restrict__ partial, float* __restrict__ out) {
    __shared__ float s3[3];
    int tid = threadIdx.x;
    if (tid < 3) s3[tid] = 0.f;
    __syncthreads();
    if (tid < 3 * NSLOT) {
        float v = partial[tid * SLOT_STRIDE];
        atomicAdd(&s3[tid / NSLOT], v);
    }
    __syncthreads();
    if (tid == 0) {
        double inv = 1.0 / ((double)NN * (double)NN * 2.5066282746310002);  // N^2 * sqrt(2*pi)
        double mxx = (double)s3[0] * inv;
        double mzz = (double)s3[1] * inv;
        double mxz = (double)s3[2] * inv;
        double v = log(sqrt(mxx * mzz + 1e-5) / (mxz + 1e-5));
        out[0] = (float)v;
    }
}

extern "C" void kernel_launch(void* const* d_in, const int* in_sizes, int n_in,
                              void* d_out, int out_size, void* d_ws, size_t ws_size,
                              hipStream_t stream) {
    const float* X = (const float*)d_in[0];
    const float* Z = (const float*)d_in[1];
    char* ws = (char*)d_ws;
    __hip_bfloat16* Xb = (__hip_bfloat16*)(ws);
    __hip_bfloat16* Zb = (__hip_bfloat16*)(ws + 1048576);
    float* na = (float*)(ws + 2097152);
    float* nb = (float*)(ws + 2097152 + 32768);
    float* partial = (float*)(ws + 2097152 + 65536);

    hipLaunchKernelGGL(prep_kernel, dim3(512), dim3(256), 0, stream,
                       X, Z, Xb, Zb, na, nb, partial);
    hipLaunchKernelGGL(mmd_kernel, dim3(NBLOCKS), dim3(256), 0, stream, Xb, Zb, na, nb, partial);
    hipLaunchKernelGGL(final_kernel, dim3(1), dim3(128), 0, stream, partial, (float*)d_out);
}

// Round 8
// 94.407 us; speedup vs baseline: 1.8204x; 1.8204x over previous
//
#include <hip/hip_runtime.h>
#include <hip/hip_bf16.h>
#include <math.h>

#define NN 8192
#define DD 64
#define TILES_SYM 2080          // 64*65/2 per symmetric combo (128x128 block tiles)
#define T2B (2*TILES_SYM)       // 4160: end of ZZ region
#define TILES_TOTAL 8256        // 2*2080 + 4096
#define NBLOCKS 512             // exactly 2 blocks/CU at ~200 regs -> single full round
#define TPB 16                  // blocks 0..447: 16 tiles; 448..511: 17 (all XZ)
#define NSLOT 32
#define SLOT_STRIDE 16          // floats -> 64B per slot

typedef __bf16 bf16x8 __attribute__((ext_vector_type(8)));
typedef float f32x4 __attribute__((ext_vector_type(4)));

#if defined(__has_builtin)
#if __has_builtin(__builtin_amdgcn_exp2f)
#define EXP2F __builtin_amdgcn_exp2f
#endif
#endif
#ifndef EXP2F
#define EXP2F exp2f
#endif

// ws layout:
//   [0,        1048576)  Xb  bf16 [8192][64]
//   [1048576,  2097152)  Zb  bf16 [8192][64]
//   [2097152, +32768)    na  f32  [8192]   ( = -log2(e) * ||x_i||^2 )
//   [+32768,  +65536)    nb  f32  [8192]
//   [+65536,  +71680)    partial f32 [3*NSLOT*SLOT_STRIDE]

__global__ __launch_bounds__(256) void prep_kernel(
        const float* __restrict__ X, const float* __restrict__ Z,
        __hip_bfloat16* __restrict__ Xb, __hip_bfloat16* __restrict__ Zb,
        float* __restrict__ na, float* __restrict__ nb,
        float* __restrict__ partial) {
    int tid = threadIdx.x;
    int gw = blockIdx.x * 4 + (tid >> 6);
    int lane = tid & 63;
    int r8 = lane >> 3, sub = lane & 7;
    int row = gw * 8 + r8;          // [0, 16384)
    const float* src = (row < NN) ? (X + (size_t)row * DD) : (Z + (size_t)(row - NN) * DD);
    __hip_bfloat16* dst = (row < NN) ? (Xb + (size_t)row * DD) : (Zb + (size_t)(row - NN) * DD);
    const float4* p = (const float4*)(src + sub * 8);
    float4 u = p[0], v = p[1];
    float w[8] = {u.x, u.y, u.z, u.w, v.x, v.y, v.z, v.w};
    unsigned int h[8];
    float s = 0.f;
    #pragma unroll
    for (int r = 0; r < 8; ++r) {
        __hip_bfloat16 b = __float2bfloat16(w[r]);
        h[r] = *(unsigned short*)&b;
        float xr = __bfloat162float(b);
        s = fmaf(xr, xr, s);
    }
    uint4 pk;
    pk.x = h[0] | (h[1] << 16); pk.y = h[2] | (h[3] << 16);
    pk.z = h[4] | (h[5] << 16); pk.w = h[6] | (h[7] << 16);
    *(uint4*)(dst + sub * 8) = pk;
    s += __shfl_xor(s, 1, 64);
    s += __shfl_xor(s, 2, 64);
    s += __shfl_xor(s, 4, 64);
    if (sub == 0) {
        float nv = -1.4426950408889634f * s;
        if (row < NN) na[row] = nv; else nb[row - NN] = nv;
    }
    if (blockIdx.x == 0) {
        for (int i = tid; i < 3 * NSLOT * SLOT_STRIDE; i += 256) partial[i] = 0.f;
    }
}

// R3's proven codegen (fully unrolled, static dbuf indices, compile-time
// guards) with single-round balanced grid:
//   blocks 0..447:   t0 = bid*16, 16 tiles
//   blocks 448..511: t0 = 7168 + 17*(bid-448), 17 tiles (all XZ)
// Region boundaries align with block boundaries (2080=130*16, 4160=260*16)
// so combo is fixed per block. 4 waves as 2x2 on a 128x128 block tile.
__global__ __launch_bounds__(256) void mmd_kernel(
        const __hip_bfloat16* __restrict__ Xbh, const __hip_bfloat16* __restrict__ Zbh,
        const float* __restrict__ na, const float* __restrict__ nb,
        float* __restrict__ partial) {
    int tid = threadIdx.x;
    int wave = tid >> 6, lane = tid & 63;
    int wr = wave >> 1, wc = wave & 1;
    int lm = lane & 15;   // A-frag row / B-frag col / C col (within 16)
    int lk = lane >> 4;   // k-group of 8 / C row group of 4
    __shared__ float wsum[4];
    const float C2 = 2.8853900817779268f;  // 2*log2(e)
    const int bid = blockIdx.x;
    const bool ext = (bid >= 448);

    // ---- map block's first tile (once) ----
    int t0 = ext ? (7168 + 17 * (bid - 448)) : (bid * TPB);
    int combo, bi, bj;
    if (t0 < T2B) {
        combo = (t0 < TILES_SYM) ? 0 : 1;
        int tt = (t0 < TILES_SYM) ? t0 : t0 - TILES_SYM;
        int rr = (int)((129.0f - sqrtf(16641.0f - 8.0f * (float)tt)) * 0.5f);
        if (rr < 0) rr = 0;
        while (rr > 0 && rr * (129 - rr) / 2 > tt) --rr;
        while ((rr + 1) * (128 - rr) / 2 <= tt) ++rr;
        bi = rr;
        bj = rr + (tt - rr * (129 - rr) / 2);
    } else {
        combo = 2;
        int rem = t0 - T2B;
        bi = rem >> 6;
        bj = rem & 63;
    }
    const bool sym = (combo != 2);
    const __bf16 *A, *B;
    const float *sa, *sb;
    const __bf16* Xb = (const __bf16*)Xbh;
    const __bf16* Zb = (const __bf16*)Zbh;
    if (combo == 0)      { A = Xb; B = Xb; sa = na; sb = na; }
    else if (combo == 1) { A = Zb; B = Zb; sa = nb; sb = nb; }
    else                 { A = Xb; B = Zb; sa = na; sb = nb; }

    // ---- A fragments + row norms for current bi ----
    bf16x8 af[2][4];
    float nav[4][4], navrtmax[4];
    {
        int row0 = bi * 128 + wr * 64;
        #pragma unroll
        for (int ks = 0; ks < 2; ++ks)
            #pragma unroll
            for (int rt = 0; rt < 4; ++rt)
                af[ks][rt] = *(const bf16x8*)(A + (size_t)(row0 + rt * 16 + lm) * DD + ks * 32 + lk * 8);
        #pragma unroll
        for (int rt = 0; rt < 4; ++rt) {
            #pragma unroll
            for (int r = 0; r < 4; ++r) nav[rt][r] = sa[row0 + rt * 16 + lk * 4 + r];
            navrtmax[rt] = fmaxf(fmaxf(nav[rt][0], nav[rt][1]), fmaxf(nav[rt][2], nav[rt][3]));
        }
    }

    // ---- prefetch B for first tile ----
    bf16x8 bufB[2][2][4];   // [buf][ks][ct]
    float bufNb[2][4];
    {
        int col0 = bj * 128 + wc * 64;
        #pragma unroll
        for (int ks = 0; ks < 2; ++ks)
            #pragma unroll
            for (int ct = 0; ct < 4; ++ct)
                bufB[0][ks][ct] = *(const bf16x8*)(B + (size_t)(col0 + ct * 16 + lm) * DD + ks * 32 + lk * 8);
        #pragma unroll
        for (int ct = 0; ct < 4; ++ct) bufNb[0][ct] = sb[col0 + ct * 16 + lm];
    }

    float lsum = 0.f;

    #pragma unroll
    for (int it = 0; it < TPB; ++it) {
        const int cur = it & 1, nxt = cur ^ 1;
        const bool lastFixed = (it + 1 == TPB);
        bool havenext = !lastFixed || ext;   // 17th tile only for ext blocks
        bool diag = sym && (bi == bj);
        float tileScale = (sym && bj > bi) ? 2.f : 1.f;
        int row0 = bi * 128 + wr * 64;
        int col0 = bj * 128 + wc * 64;

        // next tile coords + B prefetch (independent of current tile's data)
        int nbi = bi, nbj = bj;
        if (havenext) {
            nbj = bj + 1;
            if (nbj == 64) { nbi = bi + 1; nbj = sym ? nbi : 0; }
            int ncol0 = nbj * 128 + wc * 64;
            #pragma unroll
            for (int ks = 0; ks < 2; ++ks)
                #pragma unroll
                for (int ct = 0; ct < 4; ++ct)
                    bufB[nxt][ks][ct] = *(const bf16x8*)(B + (size_t)(ncol0 + ct * 16 + lm) * DD + ks * 32 + lk * 8);
            #pragma unroll
            for (int ct = 0; ct < 4; ++ct) bufNb[nxt][ct] = sb[ncol0 + ct * 16 + lm];
        }

        // ---- MFMA ----
        f32x4 acc[4][4] = {};
        #pragma unroll
        for (int ks = 0; ks < 2; ++ks)
            #pragma unroll
            for (int rt = 0; rt < 4; ++rt)
                #pragma unroll
                for (int ct = 0; ct < 4; ++ct)
                    acc[rt][ct] = __builtin_amdgcn_mfma_f32_16x16x32_bf16(
                        af[ks][rt], bufB[cur][ks][ct], acc[rt][ct], 0, 0, 0);

        // ---- gated epilogue ----
        #pragma unroll
        for (int rt = 0; rt < 4; ++rt) {
            #pragma unroll
            for (int ct = 0; ct < 4; ++ct) {
                float fm = fmaxf(fmaxf(acc[rt][ct][0], acc[rt][ct][1]),
                                 fmaxf(acc[rt][ct][2], acc[rt][ct][3]));
                float fb = fmaf(fm, C2, navrtmax[rt] + bufNb[cur][ct]);
                if (__any(fb > -30.f)) {
                    float base = bufNb[cur][ct];
                    float a0 = fmaf(acc[rt][ct][0], C2, nav[rt][0] + base);
                    float a1 = fmaf(acc[rt][ct][1], C2, nav[rt][1] + base);
                    float a2 = fmaf(acc[rt][ct][2], C2, nav[rt][2] + base);
                    float a3 = fmaf(acc[rt][ct][3], C2, nav[rt][3] + base);
                    float e0 = EXP2F(fminf(a0, 0.f));
                    float e1 = EXP2F(fminf(a1, 0.f));
                    float e2 = EXP2F(fminf(a2, 0.f));
                    float e3 = EXP2F(fminf(a3, 0.f));
                    if (diag) {
                        int gcol = col0 + ct * 16 + lm;
                        int gr = row0 + rt * 16 + lk * 4;
                        e0 *= (gr + 0 < gcol) ? 2.f : ((gr + 0 == gcol) ? 1.f : 0.f);
                        e1 *= (gr + 1 < gcol) ? 2.f : ((gr + 1 == gcol) ? 1.f : 0.f);
                        e2 *= (gr + 2 < gcol) ? 2.f : ((gr + 2 == gcol) ? 1.f : 0.f);
                        e3 *= (gr + 3 < gcol) ? 2.f : ((gr + 3 == gcol) ? 1.f : 0.f);
                        lsum += (e0 + e1) + (e2 + e3);
                    } else {
                        lsum += tileScale * ((e0 + e1) + (e2 + e3));
                    }
                }
            }
        }

        // ---- row change: reload A (after epilogue consumed nav) ----
        if (havenext && nbi != bi) {
            int nrow0 = nbi * 128 + wr * 64;
            #pragma unroll
            for (int ks = 0; ks < 2; ++ks)
                #pragma unroll
                for (int rt = 0; rt < 4; ++rt)
                    af[ks][rt] = *(const bf16x8*)(A + (size_t)(nrow0 + rt * 16 + lm) * DD + ks * 32 + lk * 8);
            #pragma unroll
            for (int rt = 0; rt < 4; ++rt) {
                #pragma unroll
                for (int r = 0; r < 4; ++r) nav[rt][r] = sa[nrow0 + rt * 16 + lk * 4 + r];
                navrtmax[rt] = fmaxf(fmaxf(nav[rt][0], nav[rt][1]), fmaxf(nav[rt][2], nav[rt][3]));
            }
        }
        bi = nbi; bj = nbj;
    }

    // ---- 17th tile for ext blocks (always XZ: no diag, no scale) ----
    if (ext) {
        // buffer parity: after 16 iterations cur would be 0
        f32x4 acc[4][4] = {};
        #pragma unroll
        for (int ks = 0; ks < 2; ++ks)
            #pragma unroll
            for (int rt = 0; rt < 4; ++rt)
                #pragma unroll
                for (int ct = 0; ct < 4; ++ct)
                    acc[rt][ct] = __builtin_amdgcn_mfma_f32_16x16x32_bf16(
                        af[ks][rt], bufB[0][ks][ct], acc[rt][ct], 0, 0, 0);
        #pragma unroll
        for (int rt = 0; rt < 4; ++rt) {
            #pragma unroll
            for (int ct = 0; ct < 4; ++ct) {
                float fm = fmaxf(fmaxf(acc[rt][ct][0], acc[rt][ct][1]),
                                 fmaxf(acc[rt][ct][2], acc[rt][ct][3]));
                float fb = fmaf(fm, C2, navrtmax[rt] + bufNb[0][ct]);
                if (__any(fb > -30.f)) {
                    float base = bufNb[0][ct];
                    float a0 = fmaf(acc[rt][ct][0], C2, nav[rt][0] + base);
                    float a1 = fmaf(acc[rt][ct][1], C2, nav[rt][1] + base);
                    float a2 = fmaf(acc[rt][ct][2], C2, nav[rt][2] + base);
                    float a3 = fmaf(acc[rt][ct][3], C2, nav[rt][3] + base);
                    lsum += (EXP2F(fminf(a0, 0.f)) + EXP2F(fminf(a1, 0.f)))
                          + (EXP2F(fminf(a2, 0.f)) + EXP2F(fminf(a3, 0.f)));
                }
            }
        }
    }

    // ---- single flush, spread over cache-line slots ----
    #pragma unroll
    for (int off = 32; off; off >>= 1) lsum += __shfl_xor(lsum, off, 64);
    if (lane == 0) wsum[wave] = lsum;
    __syncthreads();
    if (tid == 0) {
        float s = (wsum[0] + wsum[1]) + (wsum[2] + wsum[3]);
        int slot = combo * NSLOT + (bid & (NSLOT - 1));
        atomicAdd(&partial[slot * SLOT_STRIDE], s);
    }
}

__global__ void final_kernel(const float* __restrict__ partial, float* __restrict__ out) {
    __shared__ float s3[3];
    int tid = threadIdx.x;
    if (tid < 3) s3[tid] = 0.f;
    __syncthreads();
    if (tid < 3 * NSLOT) {
        float v = partial[tid * SLOT_STRIDE];
        atomicAdd(&s3[tid / NSLOT], v);
    }
    __syncthreads();
    if (tid == 0) {
        double inv = 1.0 / ((double)NN * (double)NN * 2.5066282746310002);  // N^2 * sqrt(2*pi)
        double mxx = (double)s3[0] * inv;
        double mzz = (double)s3[1] * inv;
        double mxz = (double)s3[2] * inv;
        double v = log(sqrt(mxx * mzz + 1e-5) / (mxz + 1e-5));
        out[0] = (float)v;
    }
}

extern "C" void kernel_launch(void* const* d_in, const int* in_sizes, int n_in,
                              void* d_out, int out_size, void* d_ws, size_t ws_size,
                              hipStream_t stream) {
    const float* X = (const float*)d_in[0];
    const float* Z = (const float*)d_in[1];
    char* ws = (char*)d_ws;
    __hip_bfloat16* Xb = (__hip_bfloat16*)(ws);
    __hip_bfloat16* Zb = (__hip_bfloat16*)(ws + 1048576);
    float* na = (float*)(ws + 2097152);
    float* nb = (float*)(ws + 2097152 + 32768);
    float* partial = (float*)(ws + 2097152 + 65536);

    hipLaunchKernelGGL(prep_kernel, dim3(512), dim3(256), 0, stream,
                       X, Z, Xb, Zb, na, nb, partial);
    hipLaunchKernelGGL(mmd_kernel, dim3(NBLOCKS), dim3(256), 0, stream, Xb, Zb, na, nb, partial);
    hipLaunchKernelGGL(final_kernel, dim3(1), dim3(128), 0, stream, partial, (float*)d_out);
}

// Round 9
// 56.726 us; speedup vs baseline: 3.0296x; 1.6642x over previous
//
#include <hip/hip_runtime.h>
#include <hip/hip_bf16.h>
#include <math.h>

#define NN 8192
#define DD 64
#define TILES_SYM 2080          // 64*65/2 per symmetric combo (128x128 block tiles)
#define T2B (2*TILES_SYM)       // 4160: end of ZZ region
#define TILES_TOTAL 8256        // 2*2080 + 4096
#define TILES_PER_BLOCK 8
#define NBLOCKS (TILES_TOTAL / TILES_PER_BLOCK)   // 1032
#define NSLOT 32
#define SLOT_STRIDE 16          // floats -> 64B per slot

typedef __bf16 bf16x8 __attribute__((ext_vector_type(8)));
typedef float f32x4 __attribute__((ext_vector_type(4)));

#if defined(__has_builtin)
#if __has_builtin(__builtin_amdgcn_exp2f)
#define EXP2F __builtin_amdgcn_exp2f
#endif
#endif
#ifndef EXP2F
#define EXP2F exp2f
#endif

// ws layout:
//   [0,        1048576)  Xb  bf16 [8192][64]
//   [1048576,  2097152)  Zb  bf16 [8192][64]
//   [2097152, +32768)    na  f32  [8192]   ( = -log2(e) * ||x_i||^2 )
//   [+32768,  +65536)    nb  f32  [8192]
//   [+65536,  +71680)    partial f32 [3*NSLOT*SLOT_STRIDE]

__global__ __launch_bounds__(256) void prep_kernel(
        const float* __restrict__ X, const float* __restrict__ Z,
        __hip_bfloat16* __restrict__ Xb, __hip_bfloat16* __restrict__ Zb,
        float* __restrict__ na, float* __restrict__ nb,
        float* __restrict__ partial) {
    int tid = threadIdx.x;
    int gw = blockIdx.x * 4 + (tid >> 6);
    int lane = tid & 63;
    int r8 = lane >> 3, sub = lane & 7;
    int row = gw * 8 + r8;          // [0, 16384)
    const float* src = (row < NN) ? (X + (size_t)row * DD) : (Z + (size_t)(row - NN) * DD);
    __hip_bfloat16* dst = (row < NN) ? (Xb + (size_t)row * DD) : (Zb + (size_t)(row - NN) * DD);
    const float4* p = (const float4*)(src + sub * 8);
    float4 u = p[0], v = p[1];
    float w[8] = {u.x, u.y, u.z, u.w, v.x, v.y, v.z, v.w};
    unsigned int h[8];
    float s = 0.f;
    #pragma unroll
    for (int r = 0; r < 8; ++r) {
        __hip_bfloat16 b = __float2bfloat16(w[r]);
        h[r] = *(unsigned short*)&b;
        float xr = __bfloat162float(b);
        s = fmaf(xr, xr, s);
    }
    uint4 pk;
    pk.x = h[0] | (h[1] << 16); pk.y = h[2] | (h[3] << 16);
    pk.z = h[4] | (h[5] << 16); pk.w = h[6] | (h[7] << 16);
    *(uint4*)(dst + sub * 8) = pk;
    s += __shfl_xor(s, 1, 64);
    s += __shfl_xor(s, 2, 64);
    s += __shfl_xor(s, 4, 64);
    if (sub == 0) {
        float nv = -1.4426950408889634f * s;
        if (row < NN) na[row] = nv; else nb[row - NN] = nv;
    }
    if (blockIdx.x == 0) {
        for (int i = tid; i < 3 * NSLOT * SLOT_STRIDE; i += 256) partial[i] = 0.f;
    }
}

// R3's exact structure (proven: no spills, 57.5us) + sched_barrier(0) fences
// pinning the prefetch loads BEFORE the MFMA cluster, so the compiler cannot
// sink/rematerialize them to their use site (which would serialize every
// tile on L2 latency). Flat tile enumeration, combo fixed per block.
__global__ __launch_bounds__(256) void mmd_kernel(
        const __hip_bfloat16* __restrict__ Xbh, const __hip_bfloat16* __restrict__ Zbh,
        const float* __restrict__ na, const float* __restrict__ nb,
        float* __restrict__ partial) {
    int tid = threadIdx.x;
    int wave = tid >> 6, lane = tid & 63;
    int wr = wave >> 1, wc = wave & 1;
    int lm = lane & 15;   // A-frag row / B-frag col / C col (within 16)
    int lk = lane >> 4;   // k-group of 8 / C row group of 4
    __shared__ float wsum[4];
    const float C2 = 2.8853900817779268f;  // 2*log2(e)

    // ---- map block's first tile (once) ----
    int t0 = blockIdx.x * TILES_PER_BLOCK;
    int combo, bi, bj;
    if (t0 < T2B) {
        combo = (t0 < TILES_SYM) ? 0 : 1;
        int tt = (t0 < TILES_SYM) ? t0 : t0 - TILES_SYM;
        int rr = (int)((129.0f - sqrtf(16641.0f - 8.0f * (float)tt)) * 0.5f);
        if (rr < 0) rr = 0;
        while (rr > 0 && rr * (129 - rr) / 2 > tt) --rr;
        while ((rr + 1) * (128 - rr) / 2 <= tt) ++rr;
        bi = rr;
        bj = rr + (tt - rr * (129 - rr) / 2);
    } else {
        combo = 2;
        int rem = t0 - T2B;
        bi = rem >> 6;
        bj = rem & 63;
    }
    const bool sym = (combo != 2);
    const __bf16 *A, *B;
    const float *sa, *sb;
    const __bf16* Xb = (const __bf16*)Xbh;
    const __bf16* Zb = (const __bf16*)Zbh;
    if (combo == 0)      { A = Xb; B = Xb; sa = na; sb = na; }
    else if (combo == 1) { A = Zb; B = Zb; sa = nb; sb = nb; }
    else                 { A = Xb; B = Zb; sa = na; sb = nb; }

    // ---- A fragments + row norms for current bi ----
    bf16x8 af[2][4];
    float nav[4][4], navrtmax[4];
    {
        int row0 = bi * 128 + wr * 64;
        #pragma unroll
        for (int ks = 0; ks < 2; ++ks)
            #pragma unroll
            for (int rt = 0; rt < 4; ++rt)
                af[ks][rt] = *(const bf16x8*)(A + (size_t)(row0 + rt * 16 + lm) * DD + ks * 32 + lk * 8);
        #pragma unroll
        for (int rt = 0; rt < 4; ++rt) {
            #pragma unroll
            for (int r = 0; r < 4; ++r) nav[rt][r] = sa[row0 + rt * 16 + lk * 4 + r];
            navrtmax[rt] = fmaxf(fmaxf(nav[rt][0], nav[rt][1]), fmaxf(nav[rt][2], nav[rt][3]));
        }
    }

    // ---- prefetch B for first tile ----
    bf16x8 bufB[2][2][4];   // [buf][ks][ct]
    float bufNb[2][4];
    {
        int col0 = bj * 128 + wc * 64;
        #pragma unroll
        for (int ks = 0; ks < 2; ++ks)
            #pragma unroll
            for (int ct = 0; ct < 4; ++ct)
                bufB[0][ks][ct] = *(const bf16x8*)(B + (size_t)(col0 + ct * 16 + lm) * DD + ks * 32 + lk * 8);
        #pragma unroll
        for (int ct = 0; ct < 4; ++ct) bufNb[0][ct] = sb[col0 + ct * 16 + lm];
    }

    float lsum = 0.f;

    #pragma unroll
    for (int it = 0; it < TILES_PER_BLOCK; ++it) {
        const int cur = it & 1, nxt = cur ^ 1;
        const bool last = (it + 1 == TILES_PER_BLOCK);
        bool diag = sym && (bi == bj);
        float tileScale = (sym && bj > bi) ? 2.f : 1.f;
        int row0 = bi * 128 + wr * 64;
        int col0 = bj * 128 + wc * 64;

        // next tile coords + B prefetch (independent of current tile's data)
        int nbi = bi, nbj = bj;
        if (!last) {
            nbj = bj + 1;
            if (nbj == 64) { nbi = bi + 1; nbj = sym ? nbi : 0; }
            int ncol0 = nbj * 128 + wc * 64;
            #pragma unroll
            for (int ks = 0; ks < 2; ++ks)
                #pragma unroll
                for (int ct = 0; ct < 4; ++ct)
                    bufB[nxt][ks][ct] = *(const bf16x8*)(B + (size_t)(ncol0 + ct * 16 + lm) * DD + ks * 32 + lk * 8);
            #pragma unroll
            for (int ct = 0; ct < 4; ++ct) bufNb[nxt][ct] = sb[ncol0 + ct * 16 + lm];
        }
        // Fence: prefetch loads must ISSUE here, before the MFMA cluster.
        // Without this, hipcc sinks the loads to their use (next iteration),
        // serializing every tile on L2 latency.
        __builtin_amdgcn_sched_barrier(0);

        // ---- MFMA ----
        f32x4 acc[4][4] = {};
        #pragma unroll
        for (int ks = 0; ks < 2; ++ks)
            #pragma unroll
            for (int rt = 0; rt < 4; ++rt)
                #pragma unroll
                for (int ct = 0; ct < 4; ++ct)
                    acc[rt][ct] = __builtin_amdgcn_mfma_f32_16x16x32_bf16(
                        af[ks][rt], bufB[cur][ks][ct], acc[rt][ct], 0, 0, 0);

        // ---- gated epilogue ----
        #pragma unroll
        for (int rt = 0; rt < 4; ++rt) {
            #pragma unroll
            for (int ct = 0; ct < 4; ++ct) {
                float fm = fmaxf(fmaxf(acc[rt][ct][0], acc[rt][ct][1]),
                                 fmaxf(acc[rt][ct][2], acc[rt][ct][3]));
                float fb = fmaf(fm, C2, navrtmax[rt] + bufNb[cur][ct]);
                if (__any(fb > -30.f)) {
                    float base = bufNb[cur][ct];
                    float a0 = fmaf(acc[rt][ct][0], C2, nav[rt][0] + base);
                    float a1 = fmaf(acc[rt][ct][1], C2, nav[rt][1] + base);
                    float a2 = fmaf(acc[rt][ct][2], C2, nav[rt][2] + base);
                    float a3 = fmaf(acc[rt][ct][3], C2, nav[rt][3] + base);
                    float e0 = EXP2F(fminf(a0, 0.f));
                    float e1 = EXP2F(fminf(a1, 0.f));
                    float e2 = EXP2F(fminf(a2, 0.f));
                    float e3 = EXP2F(fminf(a3, 0.f));
                    if (diag) {
                        int gcol = col0 + ct * 16 + lm;
                        int gr = row0 + rt * 16 + lk * 4;
                        e0 *= (gr + 0 < gcol) ? 2.f : ((gr + 0 == gcol) ? 1.f : 0.f);
                        e1 *= (gr + 1 < gcol) ? 2.f : ((gr + 1 == gcol) ? 1.f : 0.f);
                        e2 *= (gr + 2 < gcol) ? 2.f : ((gr + 2 == gcol) ? 1.f : 0.f);
                        e3 *= (gr + 3 < gcol) ? 2.f : ((gr + 3 == gcol) ? 1.f : 0.f);
                        lsum += (e0 + e1) + (e2 + e3);
                    } else {
                        lsum += tileScale * ((e0 + e1) + (e2 + e3));
                    }
                }
            }
        }

        // ---- row change: reload A (after epilogue consumed nav) ----
        if (!last && nbi != bi) {
            int nrow0 = nbi * 128 + wr * 64;
            #pragma unroll
            for (int ks = 0; ks < 2; ++ks)
                #pragma unroll
                for (int rt = 0; rt < 4; ++rt)
                    af[ks][rt] = *(const bf16x8*)(A + (size_t)(nrow0 + rt * 16 + lm) * DD + ks * 32 + lk * 8);
            #pragma unroll
            for (int rt = 0; rt < 4; ++rt) {
                #pragma unroll
                for (int r = 0; r < 4; ++r) nav[rt][r] = sa[nrow0 + rt * 16 + lk * 4 + r];
                navrtmax[rt] = fmaxf(fmaxf(nav[rt][0], nav[rt][1]), fmaxf(nav[rt][2], nav[rt][3]));
            }
            __builtin_amdgcn_sched_barrier(0);
        }
        bi = nbi; bj = nbj;
    }

    // ---- single flush, spread over cache-line slots ----
    #pragma unroll
    for (int off = 32; off; off >>= 1) lsum += __shfl_xor(lsum, off, 64);
    if (lane == 0) wsum[wave] = lsum;
    __syncthreads();
    if (tid == 0) {
        float s = (wsum[0] + wsum[1]) + (wsum[2] + wsum[3]);
        int slot = combo * NSLOT + (blockIdx.x & (NSLOT - 1));
        atomicAdd(&partial[slot * SLOT_STRIDE], s);
    }
}

__global__ void final_kernel(const float* __restrict__ partial, float* __restrict__ out) {
    __shared__ float s3[3];
    int tid = threadIdx.x;
    if (tid < 3) s3[tid] = 0.f;
    __syncthreads();
    if (tid < 3 * NSLOT) {
        float v = partial[tid * SLOT_STRIDE];
        atomicAdd(&s3[tid / NSLOT], v);
    }
    __syncthreads();
    if (tid == 0) {
        double inv = 1.0 / ((double)NN * (double)NN * 2.5066282746310002);  // N^2 * sqrt(2*pi)
        double mxx = (double)s3[0] * inv;
        double mzz = (double)s3[1] * inv;
        double mxz = (double)s3[2] * inv;
        double v = log(sqrt(mxx * mzz + 1e-5) / (mxz + 1e-5));
        out[0] = (float)v;
    }
}

extern "C" void kernel_launch(void* const* d_in, const int* in_sizes, int n_in,
                              void* d_out, int out_size, void* d_ws, size_t ws_size,
                              hipStream_t stream) {
    const float* X = (const float*)d_in[0];
    const float* Z = (const float*)d_in[1];
    char* ws = (char*)d_ws;
    __hip_bfloat16* Xb = (__hip_bfloat16*)(ws);
    __hip_bfloat16* Zb = (__hip_bfloat16*)(ws + 1048576);
    float* na = (float*)(ws + 2097152);
    float* nb = (float*)(ws + 2097152 + 32768);
    float* partial = (float*)(ws + 2097152 + 65536);

    hipLaunchKernelGGL(prep_kernel, dim3(512), dim3(256), 0, stream,
                       X, Z, Xb, Zb, na, nb, partial);
    hipLaunchKernelGGL(mmd_kernel, dim3(NBLOCKS), dim3(256), 0, stream, Xb, Zb, na, nb, partial);
    hipLaunchKernelGGL(final_kernel, dim3(1), dim3(128), 0, stream, partial, (float*)d_out);
}